// Round 12
// baseline (105.316 us; speedup 1.0000x reference)
//
#include <hip/hip_runtime.h>

// CRF NLL: 5-way segmented chains with rank-1 bridges, ONE CHAIN PER SIMD
// (R22 structure, passed absmax 0.0), per-step matvec cut ~2x via f16
// PACKED broadcasts (R23/R24/R25). R26 = R25 with the kPre-accounting
// SIGN FLIPPED:
//   Each active step multiplies the state by a kPre-scaled emission, so
//   log(q_final) + C = log(true) + cnt*log(kPre). Correction must be
//   -cnt*log(kPre) = +cnt*4ln2. R24 omitted it (absmax 1056 = deficit),
//   R25 added cnt*log(kPre) (negative) DOUBLING the deficit (absmax
//   2108 = 2x1054 predicted). Both numeric matches certify the rest of
//   the pipeline (f16 pack/DPP/pk_fma, pre-multiply form, bridges) is
//   correct. y-probe chains' scales cancel in the bridge (their g_cc is
//   unused); alpha/z/gamma chains carry the correction.
// Machinery (R23):
//   - state pairs (z[2k], z[2k+1]) packed f16x2 by 1 DPP row_shl:1 + 1
//     v_cvt_pkrtz; (even,odd) pairs never cross a 16-lane DPP row
//   - 17 readlane broadcasts (pairs) instead of 34 (cross-lane op count
//     is THE cost: ~9-12cyc each, schedule-invariant, R14-R19)
//   - v_pk_fma_f16 (standard per-element packed FMA) vs 17 pre-packed
//     coefficient pairs
// Range safety: fwd in PRE-multiply form (projective spread <= ~3.3 by
// Birkhoff contraction; emission applied at pack time; alpha-form
// restored after the loop). Emissions prescaled kPre=1/16 (accounted,
// sign-correct). Renorm-fold every step (guarded, off the serial chain).
// Terms 34,35 exact-zero. Meet kernel unchanged from R22.

namespace {
constexpr int kB = 128;
constexpr int kS = 512;
constexpr int kT = 36;
constexpr int kStart = 34;
constexpr int kEnd = 35;
constexpr float kPre = 0.0625f;          // emission prescale (exact pow2)
constexpr float kCorr = 2.772588722f;    // -logf(kPre) = +4 ln 2, per active step

typedef _Float16 h2 __attribute__((ext_vector_type(2)));

__device__ float g_vec[kB * 8][64];  // final chain vectors
__device__ float g_cc[kB * 8];       // per-chain log constants

__device__ __forceinline__ float readlane_f(float v, int lane) {
    return __builtin_bit_cast(float, __builtin_amdgcn_readlane(__builtin_bit_cast(int, v), lane));
}
__device__ __forceinline__ h2 readlane_h2(h2 v, int lane) {
    return __builtin_bit_cast(h2, __builtin_amdgcn_readlane(__builtin_bit_cast(int, v), lane));
}
__device__ __forceinline__ h2 pk(float lo, float hi) {
    return __builtin_bit_cast(h2, __builtin_amdgcn_cvt_pkrtz(lo, hi));
}
// lane n <- src[n+1] within each 16-lane row (row_shl:1 = 0x101);
// even lanes' +1 neighbor never crosses a row; odd-lane results unused.
__device__ __forceinline__ float shl1_f(float x) {
    const int xi = __builtin_bit_cast(int, x);
    return __builtin_bit_cast(float, __builtin_amdgcn_update_dpp(0, xi, 0x101, 0xF, 0xF, true));
}

__device__ __forceinline__ float wave_sum(float v) {
#pragma unroll
    for (int off = 32; off; off >>= 1) v += __shfl_xor(v, off, 64);
    return v;
}
__device__ __forceinline__ int wave_sum_i(int v) {
#pragma unroll
    for (int off = 32; off; off >>= 1) v += __shfl_xor(v, off, 64);
    return v;
}

// k = pair index (states 2k,2k+1; k=0..16 covers 0..33), a = acc index
#define FOR17(X) \
    X(0, 0) X(1, 1) X(2, 2) X(3, 3) X(4, 0) X(5, 1) X(6, 2) X(7, 3) \
    X(8, 0) X(9, 1) X(10, 2) X(11, 3) X(12, 0) X(13, 1) X(14, 2) X(15, 3) \
    X(16, 0)

#define PKFDECL(k, a) h2 PF##k;
#define PKFINIT(k, a) PF##k = pk(__expf(trans[(2 * (k)) * kT + jc]), __expf(trans[(2 * (k) + 1) * kT + jc]));
#define PKBDECL(k, a) h2 PB##k;
#define PKBINIT(k, a) PB##k = pk(__expf(trans[jc * kT + 2 * (k)]), __expf(trans[jc * kT + 2 * (k) + 1]));
// standard packed fma: ac.h[i] += pair.h[i] * coef.h[i]
#define FD2(k, a) asm("v_pk_fma_f16 %0, %1, %2, %0" : "+v"(ac##a) : "v"(readlane_h2(pair, 2 * (k))), "v"(PF##k));
#define BD2(k, a) asm("v_pk_fma_f16 %0, %1, %2, %0" : "+v"(ac##a) : "v"(readlane_h2(pair, 2 * (k))), "v"(PB##k));

// clamped feats row load (clamped values only feed predicated-off pad steps)
#define LDT(t) fl[(size_t)(((t) < 0) ? 0 : (((t) > kS - 1) ? (kS - 1) : (t))) * kT]

__device__ __forceinline__ int seq_len(const int* mb, int j) {
    int len = 0;
#pragma unroll
    for (int k = 0; k < kS / 64; ++k) len += mb[k * 64 + j];
    return __builtin_amdgcn_readfirstlane(wave_sum_i(len));
}

__global__ __attribute__((amdgpu_flat_work_group_size(64, 64),
                          amdgpu_waves_per_eu(1, 1)))
void crf_chain_kernel(const float* __restrict__ feats,   // (B,S,T)
                      const float* __restrict__ trans,   // (T,T)
                      const int* __restrict__ mask) {    // (B,S)
    const int b = blockIdx.x >> 3;
    const int wv = blockIdx.x & 7;            // chain role 0..7
    const int j = threadIdx.x;                // lane = state index
    const int jc = (j < kT) ? j : (kT - 1);   // clamped (addressing only)
    const float* fbase = feats + (size_t)b * kS * kT;
    const float* fl = fbase + jc;             // per-lane feats column
    const int* mb = mask + b * kS;

    const int len = seq_len(mb, j);           // in [256, 512]
    const int c = (len + 3) / 5;              // ceil((len-1)/5), in [51, 103]
    const int Gp = (c + 3) >> 2;              // 4-step groups covering c steps

    float C = 0.f;

    if (wv < 4) {
        // ==== forward chains (0 real, 1-3 probes), PRE-multiply form ====
        // step s consumes emission f_{t0+s-1} (s=0: dummy exp(0)*kPre);
        // final alpha-form restored by q *= exp(f_{t0+c-1}) after the loop.
        FOR17(PKFDECL)
        FOR17(PKFINIT)
        const int t0 = 1 + wv * c;   // chunk start (wv=0 -> t=1)
        const int cnt = c;
        float q;
        if (wv == 0) {
            const float a0 = (j < kT) ? (fl[0] + trans[kStart * kT + jc]) : -1e30f;
            C = readlane_f(a0, 0);
            q = __expf(a0 - C);
        } else {
            q = (jc == kStart) ? 0.f : 1.f;   // u, with u[START]=0
        }

        auto fstep = [&](float ef, int s) {
            const float z = q * ef;                 // emission at pack time
            const float zh = shl1_f(z);             // lane n: z[n+1]
            const h2 pair = pk(z, zh);              // (z_j, z_j+1) f16x2
            h2 ac0 = __builtin_bit_cast(h2, 0), ac1 = __builtin_bit_cast(h2, 0);
            h2 ac2 = __builtin_bit_cast(h2, 0), ac3 = __builtin_bit_cast(h2, 0);
            FOR17(FD2)
            const h2 sm = (ac0 + ac1) + (ac2 + ac3);
            const float nq = (float)sm[0] + (float)sm[1];
            q = (s < cnt) ? nq : q;                 // pad steps hold
        };
        auto rnF = [&](float& e_next, int s_next) {  // fold: off serial chain
            if (s_next < cnt) {
                const float m = readlane_f(q, 0);   // q0 > 0, spread <= ~3.3
                C += __logf(m);
                e_next *= __builtin_amdgcn_rcpf(m);
            }
        };

        float p0, p1, p2, p3, e0, e1, e2, e3;
        p0 = 0.f;          p1 = LDT(t0);     p2 = LDT(t0 + 1); p3 = LDT(t0 + 2);
        e0 = __expf(p0) * kPre; e1 = __expf(p1) * kPre;
        e2 = __expf(p2) * kPre; e3 = __expf(p3) * kPre;
        p0 = LDT(t0 + 3); p1 = LDT(t0 + 4); p2 = LDT(t0 + 5); p3 = LDT(t0 + 6);

#pragma unroll 1
        for (int g = 0; g < Gp; ++g) {
            const int s = 4 * g;
            fstep(e0, s);     rnF(e1, s + 1);
            fstep(e1, s + 1); rnF(e2, s + 2);
            fstep(e2, s + 2); rnF(e3, s + 3);
            fstep(e3, s + 3);
            e0 = __expf(p0) * kPre; e1 = __expf(p1) * kPre;
            e2 = __expf(p2) * kPre; e3 = __expf(p3) * kPre;
            p0 = LDT(t0 + s + 7);  p1 = LDT(t0 + s + 8);
            p2 = LDT(t0 + s + 9);  p3 = LDT(t0 + s + 10);
            rnF(e0, s + 4);
        }
        q *= __expf(LDT(t0 + cnt - 1));   // restore alpha-form (no kPre)
        g_vec[blockIdx.x][j] = q;
        // cnt active steps each consumed one kPre-scaled emission;
        // log(true) = log(q) + C - cnt*log(kPre) = C + cnt*kCorr + log(q):
        if (j == 0) g_cc[blockIdx.x] = C + (float)cnt * kCorr;
    } else {
        // ==== backward chains (4-6 probes, 7 real), already pre-multiply ==
        FOR17(PKBDECL)
        FOR17(PKBINIT)
        const bool real = (wv == 7);
        const int tau0 = real ? (len - 1) : ((wv - 2) * c);  // 4:2c 5:3c 6:4c
        const int cnt = real ? (len - 1 - 4 * c) : c;        // in [c-4, c]
        float gg = real ? __expf(trans[jc * kT + kEnd])      // g[END]=0 exact
                        : ((jc == kEnd) ? 0.f : 1.f);        // v, v[END]=0

        auto bstep = [&](float eb, int s) {
            const float z = eb * gg;
            const float zh = shl1_f(z);
            const h2 pair = pk(z, zh);
            h2 ac0 = __builtin_bit_cast(h2, 0), ac1 = __builtin_bit_cast(h2, 0);
            h2 ac2 = __builtin_bit_cast(h2, 0), ac3 = __builtin_bit_cast(h2, 0);
            FOR17(BD2)
            const h2 sm = (ac0 + ac1) + (ac2 + ac3);
            const float ng = (float)sm[0] + (float)sm[1];
            gg = (s < cnt) ? ng : gg;               // pad steps hold
        };
        auto rnB = [&](float& e_next, int s_next) {
            if (s_next < cnt) {
                const float m = readlane_f(gg, 0);
                C += __logf(m);
                e_next *= __builtin_amdgcn_rcpf(m);
            }
        };

        float p0, p1, p2, p3, e0, e1, e2, e3;
        p0 = LDT(tau0 - 0); p1 = LDT(tau0 - 1); p2 = LDT(tau0 - 2); p3 = LDT(tau0 - 3);
        e0 = __expf(p0) * kPre; e1 = __expf(p1) * kPre;
        e2 = __expf(p2) * kPre; e3 = __expf(p3) * kPre;
        p0 = LDT(tau0 - 4); p1 = LDT(tau0 - 5); p2 = LDT(tau0 - 6); p3 = LDT(tau0 - 7);

#pragma unroll 1
        for (int g = 0; g < Gp; ++g) {
            const int s = 4 * g;
            bstep(e0, s);     rnB(e1, s + 1);
            bstep(e1, s + 1); rnB(e2, s + 2);
            bstep(e2, s + 2); rnB(e3, s + 3);
            bstep(e3, s + 3);
            e0 = __expf(p0) * kPre; e1 = __expf(p1) * kPre;
            e2 = __expf(p2) * kPre; e3 = __expf(p3) * kPre;
            p0 = LDT(tau0 - s - 8);  p1 = LDT(tau0 - s - 9);
            p2 = LDT(tau0 - s - 10); p3 = LDT(tau0 - s - 11);
            rnB(e0, s + 4);
        }
        g_vec[blockIdx.x][j] = gg;
        // cnt active steps each consumed one kPre-scaled emission:
        if (j == 0) g_cc[blockIdx.x] = C + (float)cnt * kCorr;
    }
}

__global__ __attribute__((amdgpu_flat_work_group_size(64, 64)))
void crf_meet_kernel(const float* __restrict__ feats,   // (B,S,T)
                     const float* __restrict__ trans,   // (T,T)
                     const int* __restrict__ mask,      // (B,S)
                     const int* __restrict__ tags,      // (B,S)
                     float* __restrict__ out) {         // scalar
    const int b = blockIdx.x;
    const int j = threadIdx.x;
    const float* fbase = feats + (size_t)b * kS * kT;
    const int* mb = mask + b * kS;
    const int* tb = tags + b * kS;
    const int len = seq_len(mb, j);
    const int base = b * 8;

    // ---- meet via rank-1 bridges (lanes >= 36 masked out) ----
    const float msk = (j < kT) ? 1.f : 0.f;
    const float d1 = wave_sum(msk * g_vec[base + 4][j] * g_vec[base + 0][j]);  // z1 . alpha
    const float d2 = wave_sum(msk * g_vec[base + 5][j] * g_vec[base + 1][j]);  // z2 . y1
    const float d3 = wave_sum(msk * g_vec[base + 6][j] * g_vec[base + 2][j]);  // z3 . y2
    const float d4 = wave_sum(msk * g_vec[base + 7][j] * g_vec[base + 3][j]);  // gamma . y3
    const float n1 = wave_sum(msk * g_vec[base + 1][j]);                       // v . y1
    const float n2 = wave_sum(msk * g_vec[base + 2][j]);
    const float n3 = wave_sum(msk * g_vec[base + 3][j]);
    const float forward_b = g_cc[base + 0] + g_cc[base + 4] + g_cc[base + 5]
        + g_cc[base + 6] + g_cc[base + 7]
        + __logf(d1) + __logf(d2) + __logf(d3) + __logf(d4)
        - __logf(n1) - __logf(n2) - __logf(n3);

    // ---- gold score (parallel over time steps) ----
    float gold = 0.f;
    for (int k = j; k < kS; k += 64) {
        if (k < len) {
            const int tg = tb[k];
            const int pv = (k == 0) ? kStart : tb[k - 1];
            gold += fbase[(size_t)k * kT + tg] + trans[pv * kT + tg];
        }
    }
    gold = wave_sum(gold);

    if (j == 0) {
        gold += trans[tb[len - 1] * kT + kEnd];
        atomicAdd(out, (forward_b - gold) * (1.0f / kB));
    }
}

}  // namespace

extern "C" void kernel_launch(void* const* d_in, const int* in_sizes, int n_in,
                              void* d_out, int out_size, void* d_ws, size_t ws_size,
                              hipStream_t stream) {
    const float* feats = (const float*)d_in[0];
    const float* trans = (const float*)d_in[1];
    const int* mask = (const int*)d_in[2];
    const int* tags = (const int*)d_in[3];
    float* out = (float*)d_out;

    (void)hipMemsetAsync(out, 0, sizeof(float), stream);
    crf_chain_kernel<<<dim3(kB * 8), dim3(64), 0, stream>>>(feats, trans, mask);
    crf_meet_kernel<<<dim3(kB), dim3(64), 0, stream>>>(feats, trans, mask, tags, out);
}

// Round 13
// 99.949 us; speedup vs baseline: 1.0537x; 1.0537x over previous
//
#include <hip/hip_runtime.h>

// CRF NLL: 5-way segmented chains with rank-1 bridges, ONE CHAIN PER SIMD
// (R22 structure), f16 PACKED broadcasts halving the cross-lane count
// (R23-R26 lineage; R26 passed absmax 0.0). R27 = R26 with the inline-asm
// v_pk_fma REPLACED BY NATIVE h2 ARITHMETIC:
//   R26 ran ~11us SLOWER than the f32 R22 despite 17 vs 34 readlanes --
//   the asm's "v" constraint forced 17 s->v movs/step (readlane returns
//   SGPR) and the opaque asm blocked interleaving with the readlane
//   stream and prefetch exps (same mistake class as R15's sched_barrier).
//   Native `acc = pair*coef + acc` on ext-vector _Float16 compiles to
//   v_pk_fma_f16 (ffp-contract=fast), consumes the readlane result
//   directly as the one legal VOP3P SGPR operand (no movs), and gives
//   the scheduler full freedom. Cross-lane count stays 17.
// Chain math (R21/R22, exact on harness data):
//   chunks c = ceil((len-1)/5) <= 103 across 8 SIMD-dedicated waves:
//   role 0 real fwd alpha; 1-3 fwd probes y_i (u=1, u[START]=0);
//   4-6 bwd probes z_i (v=1, v[END]=0); 7 real bwd gamma (mask holds =
//   exact no-ops). Meet: log Z = C_a+C_z*+C_g + log(z1.a)+log(z2.y1)
//   +log(z3.y2)+log(g.y3) - log(sum y1..y3).
// f16 range safety (R23): fwd in PRE-multiply form (Birkhoff-contracted
// spread <= ~3.3); emissions prescaled kPre=1/16; renorm-fold every step
// (guarded, off the serial chain); per-chain correction +cnt*4ln2
// (sign verified by R24=1056/R25=2108 exact error arithmetic).
// Terms 34,35 exact-zero. Meet kernel unchanged from R22.

namespace {
constexpr int kB = 128;
constexpr int kS = 512;
constexpr int kT = 36;
constexpr int kStart = 34;
constexpr int kEnd = 35;
constexpr float kPre = 0.0625f;          // emission prescale (exact pow2)
constexpr float kCorr = 2.772588722f;    // -logf(kPre) = +4 ln 2, per active step

typedef _Float16 h2 __attribute__((ext_vector_type(2)));

__device__ float g_vec[kB * 8][64];  // final chain vectors
__device__ float g_cc[kB * 8];       // per-chain log constants

__device__ __forceinline__ float readlane_f(float v, int lane) {
    return __builtin_bit_cast(float, __builtin_amdgcn_readlane(__builtin_bit_cast(int, v), lane));
}
__device__ __forceinline__ h2 readlane_h2(h2 v, int lane) {
    return __builtin_bit_cast(h2, __builtin_amdgcn_readlane(__builtin_bit_cast(int, v), lane));
}
__device__ __forceinline__ h2 pk(float lo, float hi) {
    return __builtin_bit_cast(h2, __builtin_amdgcn_cvt_pkrtz(lo, hi));
}
// lane n <- src[n+1] within each 16-lane row (row_shl:1 = 0x101);
// even lanes' +1 neighbor never crosses a row; odd-lane results unused.
__device__ __forceinline__ float shl1_f(float x) {
    const int xi = __builtin_bit_cast(int, x);
    return __builtin_bit_cast(float, __builtin_amdgcn_update_dpp(0, xi, 0x101, 0xF, 0xF, true));
}

__device__ __forceinline__ float wave_sum(float v) {
#pragma unroll
    for (int off = 32; off; off >>= 1) v += __shfl_xor(v, off, 64);
    return v;
}
__device__ __forceinline__ int wave_sum_i(int v) {
#pragma unroll
    for (int off = 32; off; off >>= 1) v += __shfl_xor(v, off, 64);
    return v;
}

// k = pair index (states 2k,2k+1; k=0..16 covers 0..33), a = acc index
#define FOR17(X) \
    X(0, 0) X(1, 1) X(2, 2) X(3, 3) X(4, 0) X(5, 1) X(6, 2) X(7, 3) \
    X(8, 0) X(9, 1) X(10, 2) X(11, 3) X(12, 0) X(13, 1) X(14, 2) X(15, 3) \
    X(16, 0)

#define PKFDECL(k, a) h2 PF##k;
#define PKFINIT(k, a) PF##k = pk(__expf(trans[(2 * (k)) * kT + jc]), __expf(trans[(2 * (k) + 1) * kT + jc]));
#define PKBDECL(k, a) h2 PB##k;
#define PKBINIT(k, a) PB##k = pk(__expf(trans[jc * kT + 2 * (k)]), __expf(trans[jc * kT + 2 * (k) + 1]));
// native packed fma: compiler emits v_pk_fma_f16, readlane result stays
// in SGPR (the one legal VOP3P scalar operand) -- no movs, free scheduling
#define FD2(k, a) ac##a = readlane_h2(pair, 2 * (k)) * PF##k + ac##a;
#define BD2(k, a) ac##a = readlane_h2(pair, 2 * (k)) * PB##k + ac##a;

// clamped feats row load (clamped values only feed predicated-off pad steps)
#define LDT(t) fl[(size_t)(((t) < 0) ? 0 : (((t) > kS - 1) ? (kS - 1) : (t))) * kT]

__device__ __forceinline__ int seq_len(const int* mb, int j) {
    int len = 0;
#pragma unroll
    for (int k = 0; k < kS / 64; ++k) len += mb[k * 64 + j];
    return __builtin_amdgcn_readfirstlane(wave_sum_i(len));
}

__global__ __attribute__((amdgpu_flat_work_group_size(64, 64),
                          amdgpu_waves_per_eu(1, 1)))
void crf_chain_kernel(const float* __restrict__ feats,   // (B,S,T)
                      const float* __restrict__ trans,   // (T,T)
                      const int* __restrict__ mask) {    // (B,S)
    const int b = blockIdx.x >> 3;
    const int wv = blockIdx.x & 7;            // chain role 0..7
    const int j = threadIdx.x;                // lane = state index
    const int jc = (j < kT) ? j : (kT - 1);   // clamped (addressing only)
    const float* fbase = feats + (size_t)b * kS * kT;
    const float* fl = fbase + jc;             // per-lane feats column
    const int* mb = mask + b * kS;

    const int len = seq_len(mb, j);           // in [256, 512]
    const int c = (len + 3) / 5;              // ceil((len-1)/5), in [51, 103]
    const int Gp = (c + 3) >> 2;              // 4-step groups covering c steps

    float C = 0.f;

    if (wv < 4) {
        // ==== forward chains (0 real, 1-3 probes), PRE-multiply form ====
        // step s consumes emission f_{t0+s-1} (s=0: dummy exp(0)*kPre);
        // final alpha-form restored by q *= exp(f_{t0+c-1}) after the loop.
        FOR17(PKFDECL)
        FOR17(PKFINIT)
        const int t0 = 1 + wv * c;   // chunk start (wv=0 -> t=1)
        const int cnt = c;
        float q;
        if (wv == 0) {
            const float a0 = (j < kT) ? (fl[0] + trans[kStart * kT + jc]) : -1e30f;
            C = readlane_f(a0, 0);
            q = __expf(a0 - C);
        } else {
            q = (jc == kStart) ? 0.f : 1.f;   // u, with u[START]=0
        }

        auto fstep = [&](float ef, int s) {
            const float z = q * ef;                 // emission at pack time
            const float zh = shl1_f(z);             // lane n: z[n+1]
            const h2 pair = pk(z, zh);              // (z_j, z_j+1) f16x2
            h2 ac0 = __builtin_bit_cast(h2, 0), ac1 = __builtin_bit_cast(h2, 0);
            h2 ac2 = __builtin_bit_cast(h2, 0), ac3 = __builtin_bit_cast(h2, 0);
            FOR17(FD2)
            const h2 sm = (ac0 + ac1) + (ac2 + ac3);
            const float nq = (float)sm[0] + (float)sm[1];
            q = (s < cnt) ? nq : q;                 // pad steps hold
        };
        auto rnF = [&](float& e_next, int s_next) {  // fold: off serial chain
            if (s_next < cnt) {
                const float m = readlane_f(q, 0);   // q0 > 0, spread <= ~3.3
                C += __logf(m);
                e_next *= __builtin_amdgcn_rcpf(m);
            }
        };

        float p0, p1, p2, p3, e0, e1, e2, e3;
        p0 = 0.f;          p1 = LDT(t0);     p2 = LDT(t0 + 1); p3 = LDT(t0 + 2);
        e0 = __expf(p0) * kPre; e1 = __expf(p1) * kPre;
        e2 = __expf(p2) * kPre; e3 = __expf(p3) * kPre;
        p0 = LDT(t0 + 3); p1 = LDT(t0 + 4); p2 = LDT(t0 + 5); p3 = LDT(t0 + 6);

#pragma unroll 1
        for (int g = 0; g < Gp; ++g) {
            const int s = 4 * g;
            fstep(e0, s);     rnF(e1, s + 1);
            fstep(e1, s + 1); rnF(e2, s + 2);
            fstep(e2, s + 2); rnF(e3, s + 3);
            fstep(e3, s + 3);
            e0 = __expf(p0) * kPre; e1 = __expf(p1) * kPre;
            e2 = __expf(p2) * kPre; e3 = __expf(p3) * kPre;
            p0 = LDT(t0 + s + 7);  p1 = LDT(t0 + s + 8);
            p2 = LDT(t0 + s + 9);  p3 = LDT(t0 + s + 10);
            rnF(e0, s + 4);
        }
        q *= __expf(LDT(t0 + cnt - 1));   // restore alpha-form (no kPre)
        g_vec[blockIdx.x][j] = q;
        // cnt active steps each consumed one kPre-scaled emission;
        // log(true) = C + cnt*kCorr + log(q):
        if (j == 0) g_cc[blockIdx.x] = C + (float)cnt * kCorr;
    } else {
        // ==== backward chains (4-6 probes, 7 real), already pre-multiply ==
        FOR17(PKBDECL)
        FOR17(PKBINIT)
        const bool real = (wv == 7);
        const int tau0 = real ? (len - 1) : ((wv - 2) * c);  // 4:2c 5:3c 6:4c
        const int cnt = real ? (len - 1 - 4 * c) : c;        // in [c-4, c]
        float gg = real ? __expf(trans[jc * kT + kEnd])      // g[END]=0 exact
                        : ((jc == kEnd) ? 0.f : 1.f);        // v, v[END]=0

        auto bstep = [&](float eb, int s) {
            const float z = eb * gg;
            const float zh = shl1_f(z);
            const h2 pair = pk(z, zh);
            h2 ac0 = __builtin_bit_cast(h2, 0), ac1 = __builtin_bit_cast(h2, 0);
            h2 ac2 = __builtin_bit_cast(h2, 0), ac3 = __builtin_bit_cast(h2, 0);
            FOR17(BD2)
            const h2 sm = (ac0 + ac1) + (ac2 + ac3);
            const float ng = (float)sm[0] + (float)sm[1];
            gg = (s < cnt) ? ng : gg;               // pad steps hold
        };
        auto rnB = [&](float& e_next, int s_next) {
            if (s_next < cnt) {
                const float m = readlane_f(gg, 0);
                C += __logf(m);
                e_next *= __builtin_amdgcn_rcpf(m);
            }
        };

        float p0, p1, p2, p3, e0, e1, e2, e3;
        p0 = LDT(tau0 - 0); p1 = LDT(tau0 - 1); p2 = LDT(tau0 - 2); p3 = LDT(tau0 - 3);
        e0 = __expf(p0) * kPre; e1 = __expf(p1) * kPre;
        e2 = __expf(p2) * kPre; e3 = __expf(p3) * kPre;
        p0 = LDT(tau0 - 4); p1 = LDT(tau0 - 5); p2 = LDT(tau0 - 6); p3 = LDT(tau0 - 7);

#pragma unroll 1
        for (int g = 0; g < Gp; ++g) {
            const int s = 4 * g;
            bstep(e0, s);     rnB(e1, s + 1);
            bstep(e1, s + 1); rnB(e2, s + 2);
            bstep(e2, s + 2); rnB(e3, s + 3);
            bstep(e3, s + 3);
            e0 = __expf(p0) * kPre; e1 = __expf(p1) * kPre;
            e2 = __expf(p2) * kPre; e3 = __expf(p3) * kPre;
            p0 = LDT(tau0 - s - 8);  p1 = LDT(tau0 - s - 9);
            p2 = LDT(tau0 - s - 10); p3 = LDT(tau0 - s - 11);
            rnB(e0, s + 4);
        }
        g_vec[blockIdx.x][j] = gg;
        // cnt active steps each consumed one kPre-scaled emission:
        if (j == 0) g_cc[blockIdx.x] = C + (float)cnt * kCorr;
    }
}

__global__ __attribute__((amdgpu_flat_work_group_size(64, 64)))
void crf_meet_kernel(const float* __restrict__ feats,   // (B,S,T)
                     const float* __restrict__ trans,   // (T,T)
                     const int* __restrict__ mask,      // (B,S)
                     const int* __restrict__ tags,      // (B,S)
                     float* __restrict__ out) {         // scalar
    const int b = blockIdx.x;
    const int j = threadIdx.x;
    const float* fbase = feats + (size_t)b * kS * kT;
    const int* mb = mask + b * kS;
    const int* tb = tags + b * kS;
    const int len = seq_len(mb, j);
    const int base = b * 8;

    // ---- meet via rank-1 bridges (lanes >= 36 masked out) ----
    const float msk = (j < kT) ? 1.f : 0.f;
    const float d1 = wave_sum(msk * g_vec[base + 4][j] * g_vec[base + 0][j]);  // z1 . alpha
    const float d2 = wave_sum(msk * g_vec[base + 5][j] * g_vec[base + 1][j]);  // z2 . y1
    const float d3 = wave_sum(msk * g_vec[base + 6][j] * g_vec[base + 2][j]);  // z3 . y2
    const float d4 = wave_sum(msk * g_vec[base + 7][j] * g_vec[base + 3][j]);  // gamma . y3
    const float n1 = wave_sum(msk * g_vec[base + 1][j]);                       // v . y1
    const float n2 = wave_sum(msk * g_vec[base + 2][j]);
    const float n3 = wave_sum(msk * g_vec[base + 3][j]);
    const float forward_b = g_cc[base + 0] + g_cc[base + 4] + g_cc[base + 5]
        + g_cc[base + 6] + g_cc[base + 7]
        + __logf(d1) + __logf(d2) + __logf(d3) + __logf(d4)
        - __logf(n1) - __logf(n2) - __logf(n3);

    // ---- gold score (parallel over time steps) ----
    float gold = 0.f;
    for (int k = j; k < kS; k += 64) {
        if (k < len) {
            const int tg = tb[k];
            const int pv = (k == 0) ? kStart : tb[k - 1];
            gold += fbase[(size_t)k * kT + tg] + trans[pv * kT + tg];
        }
    }
    gold = wave_sum(gold);

    if (j == 0) {
        gold += trans[tb[len - 1] * kT + kEnd];
        atomicAdd(out, (forward_b - gold) * (1.0f / kB));
    }
}

}  // namespace

extern "C" void kernel_launch(void* const* d_in, const int* in_sizes, int n_in,
                              void* d_out, int out_size, void* d_ws, size_t ws_size,
                              hipStream_t stream) {
    const float* feats = (const float*)d_in[0];
    const float* trans = (const float*)d_in[1];
    const int* mask = (const int*)d_in[2];
    const int* tags = (const int*)d_in[3];
    float* out = (float*)d_out;

    (void)hipMemsetAsync(out, 0, sizeof(float), stream);
    crf_chain_kernel<<<dim3(kB * 8), dim3(64), 0, stream>>>(feats, trans, mask);
    crf_meet_kernel<<<dim3(kB), dim3(64), 0, stream>>>(feats, trans, mask, tags, out);
}